// Round 2
// baseline (653.970 us; speedup 1.0000x reference)
//
#include <hip/hip_runtime.h>
#include <math.h>

#define IMG_H 1080
#define IMG_W 1920
#define NFLOW 5
#define HW (IMG_H * IMG_W)

// ---------- pre-pass: pack frame1 [3][H][W] f32 -> [H][W] uchar4 (RGB_) ----------
__global__ __launch_bounds__(256) void pack_u8_kernel(const float* __restrict__ f1,
                                                      unsigned int* __restrict__ img)
{
    const int p = blockIdx.x * 256 + threadIdx.x;
    if (p >= HW) return;
    const unsigned r = (unsigned)(int)(f1[p] + 0.5f);
    const unsigned g = (unsigned)(int)(f1[HW + p] + 0.5f);
    const unsigned b = (unsigned)(int)(f1[2 * HW + p] + 0.5f);
    img[p] = r | (g << 8) | (b << 16);
}

// ---------- main: per-flow SSE with packed-u8 gathers ----------
__global__ __launch_bounds__(256) void psnr_main_kernel(
    const float2* __restrict__ flow,        // [N][H][W] float2
    const unsigned int* __restrict__ img,   // [H][W] packed u8 RGB
    const float* __restrict__ f2,           // [3][H][W]
    float* __restrict__ sums)               // [N]
{
    const int p = blockIdx.x * 256 + threadIdx.x;
    float acc[NFLOW];
#pragma unroll
    for (int n = 0; n < NFLOW; ++n) acc[n] = 0.0f;

    if (p < HW) {
        const int h = p / IMG_W;
        const int w = p - h * IMG_W;
        const float r0 = f2[p];
        const float r1 = f2[HW + p];
        const float r2 = f2[2 * HW + p];

#pragma unroll
        for (int n = 0; n < NFLOW; ++n) {
            const float2 fl = flow[n * HW + p];
            const float px = (float)w + fl.x;
            const float py = (float)h + fl.y;
            const float x0f = floorf(px);
            const float y0f = floorf(py);
            const float wx1 = px - x0f;
            const float wy1 = py - y0f;
            const float wx0 = 1.0f - wx1;
            const float wy0 = 1.0f - wy1;
            const float x1f = x0f + 1.0f;
            const float y1f = y0f + 1.0f;

            const bool vx0 = (x0f >= 0.0f) && (x0f <= (float)(IMG_W - 1));
            const bool vx1 = (x1f >= 0.0f) && (x1f <= (float)(IMG_W - 1));
            const bool vy0 = (y0f >= 0.0f) && (y0f <= (float)(IMG_H - 1));
            const bool vy1 = (y1f >= 0.0f) && (y1f <= (float)(IMG_H - 1));

            const int x0 = (int)fminf(fmaxf(x0f, 0.0f), (float)(IMG_W - 1));
            const int x1 = (int)fminf(fmaxf(x1f, 0.0f), (float)(IMG_W - 1));
            const int y0 = (int)fminf(fmaxf(y0f, 0.0f), (float)(IMG_H - 1));
            const int y1 = (int)fminf(fmaxf(y1f, 0.0f), (float)(IMG_H - 1));

            const unsigned v00 = img[y0 * IMG_W + x0];
            const unsigned v10 = img[y0 * IMG_W + x1];
            const unsigned v01 = img[y1 * IMG_W + x0];
            const unsigned v11 = img[y1 * IMG_W + x1];

            const float w00 = (vx0 && vy0) ? (wx0 * wy0) : 0.0f;
            const float w10 = (vx1 && vy0) ? (wx1 * wy0) : 0.0f;
            const float w01 = (vx0 && vy1) ? (wx0 * wy1) : 0.0f;
            const float w11 = (vx1 && vy1) ? (wx1 * wy1) : 0.0f;

            // channel 0 (ubyte0), 1 (ubyte1), 2 (ubyte2) -> v_cvt_f32_ubyteN
            const float e0 = (float)(v00 & 255u) * w00 + (float)(v10 & 255u) * w10 +
                             (float)(v01 & 255u) * w01 + (float)(v11 & 255u) * w11;
            const float e1 = (float)((v00 >> 8) & 255u) * w00 + (float)((v10 >> 8) & 255u) * w10 +
                             (float)((v01 >> 8) & 255u) * w01 + (float)((v11 >> 8) & 255u) * w11;
            const float e2 = (float)((v00 >> 16) & 255u) * w00 + (float)((v10 >> 16) & 255u) * w10 +
                             (float)((v01 >> 16) & 255u) * w01 + (float)((v11 >> 16) & 255u) * w11;

            const float d0 = r0 - truncf(e0);
            const float d1 = r1 - truncf(e1);
            const float d2 = r2 - truncf(e2);
            acc[n] += d0 * d0 + d1 * d1 + d2 * d2;
        }
    }

    // wave64 reduce, then cross-wave LDS reduce, one atomic per block per flow
#pragma unroll
    for (int n = 0; n < NFLOW; ++n) {
#pragma unroll
        for (int off = 32; off > 0; off >>= 1)
            acc[n] += __shfl_down(acc[n], off, 64);
    }

    __shared__ float sacc[NFLOW][4];
    const int lane = threadIdx.x & 63;
    const int wid = threadIdx.x >> 6;
    if (lane == 0) {
#pragma unroll
        for (int n = 0; n < NFLOW; ++n) sacc[n][wid] = acc[n];
    }
    __syncthreads();
    if (threadIdx.x == 0) {
#pragma unroll
        for (int n = 0; n < NFLOW; ++n) {
            atomicAdd(&sums[n], sacc[n][0] + sacc[n][1] + sacc[n][2] + sacc[n][3]);
        }
    }
}

// ---------- fallback (round-0 f32 gather path), used only if ws too small ----------
__global__ __launch_bounds__(256) void psnr_partial_kernel(
    const float* __restrict__ flow,
    const float* __restrict__ f1,
    const float* __restrict__ f2,
    float* __restrict__ sums)
{
    float acc[NFLOW];
#pragma unroll
    for (int n = 0; n < NFLOW; ++n) acc[n] = 0.0f;
    const int tid = blockIdx.x * blockDim.x + threadIdx.x;
    const int stride = gridDim.x * blockDim.x;
    for (int p = tid; p < HW; p += stride) {
        const int h = p / IMG_W;
        const int w = p - h * IMG_W;
        const float r0 = f2[p], r1 = f2[HW + p], r2 = f2[2 * HW + p];
#pragma unroll
        for (int n = 0; n < NFLOW; ++n) {
            const float2 fl = ((const float2*)flow)[n * HW + p];
            const float px = (float)w + fl.x;
            const float py = (float)h + fl.y;
            const float x0f = floorf(px), y0f = floorf(py);
            const float wx1 = px - x0f, wy1 = py - y0f;
            const float wx0 = 1.0f - wx1, wy0 = 1.0f - wy1;
            const float x1f = x0f + 1.0f, y1f = y0f + 1.0f;
            const bool vx0 = (x0f >= 0.0f) && (x0f <= (float)(IMG_W - 1));
            const bool vx1 = (x1f >= 0.0f) && (x1f <= (float)(IMG_W - 1));
            const bool vy0 = (y0f >= 0.0f) && (y0f <= (float)(IMG_H - 1));
            const bool vy1 = (y1f >= 0.0f) && (y1f <= (float)(IMG_H - 1));
            const int x0 = (int)fminf(fmaxf(x0f, 0.0f), (float)(IMG_W - 1));
            const int x1 = (int)fminf(fmaxf(x1f, 0.0f), (float)(IMG_W - 1));
            const int y0 = (int)fminf(fmaxf(y0f, 0.0f), (float)(IMG_H - 1));
            const int y1 = (int)fminf(fmaxf(y1f, 0.0f), (float)(IMG_H - 1));
            const int i00 = y0 * IMG_W + x0, i10 = y0 * IMG_W + x1;
            const int i01 = y1 * IMG_W + x0, i11 = y1 * IMG_W + x1;
            const float w00 = (vx0 && vy0) ? (wx0 * wy0) : 0.0f;
            const float w10 = (vx1 && vy0) ? (wx1 * wy0) : 0.0f;
            const float w01 = (vx0 && vy1) ? (wx0 * wy1) : 0.0f;
            const float w11 = (vx1 && vy1) ? (wx1 * wy1) : 0.0f;
            float a = 0.0f;
#pragma unroll
            for (int c = 0; c < 3; ++c) {
                const float* plane = f1 + c * HW;
                const float est = plane[i00] * w00 + plane[i10] * w10 +
                                  plane[i01] * w01 + plane[i11] * w11;
                const float r = (c == 0) ? r0 : ((c == 1) ? r1 : r2);
                const float d = r - truncf(est);
                a += d * d;
            }
            acc[n] += a;
        }
    }
#pragma unroll
    for (int n = 0; n < NFLOW; ++n) {
#pragma unroll
        for (int off = 32; off > 0; off >>= 1)
            acc[n] += __shfl_down(acc[n], off, 64);
    }
    __shared__ float sacc[NFLOW][4];
    const int lane = threadIdx.x & 63;
    const int wid = threadIdx.x >> 6;
    if (lane == 0) {
#pragma unroll
        for (int n = 0; n < NFLOW; ++n) sacc[n][wid] = acc[n];
    }
    __syncthreads();
    if (threadIdx.x == 0) {
#pragma unroll
        for (int n = 0; n < NFLOW; ++n)
            atomicAdd(&sums[n], sacc[n][0] + sacc[n][1] + sacc[n][2] + sacc[n][3]);
    }
}

// ---------- finalize ----------
__global__ void psnr_finalize_kernel(const float* __restrict__ sums,
                                     float* __restrict__ out)
{
    if (threadIdx.x == 0 && blockIdx.x == 0) {
        double aggr = 0.0;
        for (int n = 0; n < NFLOW; ++n) {
            const double mse = (double)sums[n] / (3.0 * (double)HW);
            const double psnr = 10.0 * log10(255.0 * 255.0 / mse);
            double wgt = 1.0;
            for (int k = 0; k < NFLOW - n; ++k) wgt *= 0.85;
            aggr += psnr * wgt;
        }
        out[0] = (float)(-aggr);
    }
}

extern "C" void kernel_launch(void* const* d_in, const int* in_sizes, int n_in,
                              void* d_out, int out_size, void* d_ws, size_t ws_size,
                              hipStream_t stream) {
    const float* flow = (const float*)d_in[0];  // [5,1080,1920,2]
    const float* f1   = (const float*)d_in[1];  // [3,1080,1920]
    const float* f2   = (const float*)d_in[2];  // [3,1080,1920]
    float* out = (float*)d_out;

    float* sums = (float*)d_ws;                                  // 5 floats @ offset 0
    unsigned int* img = (unsigned int*)((char*)d_ws + 256);      // HW u32 @ offset 256
    const size_t needed = 256 + (size_t)HW * 4;

    hipMemsetAsync(sums, 0, NFLOW * sizeof(float), stream);

    if (ws_size >= needed) {
        const int blocks = (HW + 255) / 256;  // 8100
        pack_u8_kernel<<<blocks, 256, 0, stream>>>(f1, img);
        psnr_main_kernel<<<blocks, 256, 0, stream>>>((const float2*)flow, img, f2, sums);
    } else {
        psnr_partial_kernel<<<2048, 256, 0, stream>>>(flow, f1, f2, sums);
    }
    psnr_finalize_kernel<<<1, 64, 0, stream>>>(sums, out);
}

// Round 3
// 279.086 us; speedup vs baseline: 2.3433x; 2.3433x over previous
//
#include <hip/hip_runtime.h>
#include <math.h>

#define IMG_H 1080
#define IMG_W 1920
#define NFLOW 5
#define HW (IMG_H * IMG_W)

#define TILE_W 64
#define TILE_H 32
#define HALO 32
#define REG_W (TILE_W + 2 * HALO)   // 128
#define REG_H (TILE_H + 2 * HALO)   // 96
#define THREADS 256
#define PX_PER_BLOCK (TILE_W * TILE_H)  // 2048

// ---------- pre-pass: pack frame1 [3][H][W] f32 -> [H][W] u32 (RGB in bytes 0..2) ----------
__global__ __launch_bounds__(256) void pack_u8_kernel(const float* __restrict__ f1,
                                                      unsigned int* __restrict__ img)
{
    const int p = blockIdx.x * 256 + threadIdx.x;
    if (p >= HW) return;
    const unsigned r = (unsigned)(int)(f1[p] + 0.5f);
    const unsigned g = (unsigned)(int)(f1[HW + p] + 0.5f);
    const unsigned b = (unsigned)(int)(f1[2 * HW + p] + 0.5f);
    img[p] = r | (g << 8) | (b << 16);
}

// ---------- main: LDS-tiled warped-SSE, all 5 flows fused ----------
__global__ __launch_bounds__(THREADS) void psnr_tile_kernel(
    const float2* __restrict__ flow,        // [N][H][W] float2
    const unsigned int* __restrict__ img,   // [H][W] packed u8 RGB
    const float* __restrict__ f2,           // [3][H][W]
    float* __restrict__ sums)               // [N]
{
    __shared__ unsigned int tile[REG_H * REG_W];  // 48 KB
    __shared__ float sacc[NFLOW][4];

    const int tx0 = blockIdx.x * TILE_W;
    const int ty0 = blockIdx.y * TILE_H;
    const int tid = threadIdx.x;
    const int bx = tx0 - HALO;
    const int by = ty0 - HALO;

    // stage halo region (coalesced: consecutive tid -> consecutive rx)
    for (int r = tid; r < REG_H * REG_W; r += THREADS) {
        const int ry = r >> 7;          // / REG_W
        const int rx = r & (REG_W - 1); // % REG_W
        const int gx = bx + rx;
        const int gy = by + ry;
        if ((unsigned)gx < (unsigned)IMG_W && (unsigned)gy < (unsigned)IMG_H)
            tile[r] = img[gy * IMG_W + gx];
    }
    __syncthreads();

    // staged in-image window bounds (global coords)
    const int sx0 = (bx > 0) ? bx : 0;
    const int sy0 = (by > 0) ? by : 0;
    const int sx1i = tx0 + TILE_W - 1 + HALO;
    const int sy1i = ty0 + TILE_H - 1 + HALO;
    const int sx1 = (sx1i < IMG_W - 1) ? sx1i : (IMG_W - 1);
    const int sy1 = (sy1i < IMG_H - 1) ? sy1i : (IMG_H - 1);
    const float sx0f = (float)sx0, sx1f = (float)sx1;
    const float sy0f = (float)sy0, sy1f = (float)sy1;

    float acc[NFLOW];
#pragma unroll
    for (int n = 0; n < NFLOW; ++n) acc[n] = 0.0f;

#pragma unroll
    for (int it = 0; it < PX_PER_BLOCK / THREADS; ++it) {
        const int q = it * THREADS + tid;
        const int ly = q >> 6;   // wave-uniform (64-wide rows)
        const int lx = q & 63;
        const int gx = tx0 + lx;
        const int gy = ty0 + ly;
        if (gy >= IMG_H) continue;   // wave-uniform branch (bottom edge tiles)
        const int p = gy * IMG_W + gx;

        const float r0 = f2[p];
        const float r1 = f2[HW + p];
        const float r2 = f2[2 * HW + p];

#pragma unroll
        for (int n = 0; n < NFLOW; ++n) {
            const float2 fl = flow[n * HW + p];
            const float px = (float)gx + fl.x;
            const float py = (float)gy + fl.y;
            const float x0f = floorf(px);
            const float y0f = floorf(py);
            const float wx1 = px - x0f;
            const float wy1 = py - y0f;
            const float wx0 = 1.0f - wx1;
            const float wy0 = 1.0f - wy1;
            const float x1f = x0f + 1.0f;
            const float y1f = y0f + 1.0f;

            const bool vx0 = (x0f >= 0.0f) && (x0f <= (float)(IMG_W - 1));
            const bool vx1 = (x1f >= 0.0f) && (x1f <= (float)(IMG_W - 1));
            const bool vy0 = (y0f >= 0.0f) && (y0f <= (float)(IMG_H - 1));
            const bool vy1 = (y1f >= 0.0f) && (y1f <= (float)(IMG_H - 1));

            const float w00 = (vx0 && vy0) ? (wx0 * wy0) : 0.0f;
            const float w10 = (vx1 && vy0) ? (wx1 * wy0) : 0.0f;
            const float w01 = (vx0 && vy1) ? (wx0 * wy1) : 0.0f;
            const float w11 = (vx1 && vy1) ? (wx1 * wy1) : 0.0f;

            const int x0i = (int)x0f;
            const int y0i = (int)y0f;
            const int x1i = x0i + 1;
            const int y1i = y0i + 1;

            // a VALID tap falling outside the staged window forces the (cold) global path
            const bool bad =
                ((x0f >= 0.0f) && (x0i < sx0)) ||
                ((x1f <= (float)(IMG_W - 1)) && (x1i > sx1)) ||
                ((y0f >= 0.0f) && (y0i < sy0)) ||
                ((y1f <= (float)(IMG_H - 1)) && (y1i > sy1));

            unsigned v00, v10, v01, v11;
            if (!bad) {
                // clamp to staged window -> always-initialized LDS entries
                const int rx0 = ((x0i > sx0) ? ((x0i < sx1) ? x0i : sx1) : sx0) - bx;
                const int rx1 = ((x1i > sx0) ? ((x1i < sx1) ? x1i : sx1) : sx0) - bx;
                const int ry0 = ((y0i > sy0) ? ((y0i < sy1) ? y0i : sy1) : sy0) - by;
                const int ry1 = ((y1i > sy0) ? ((y1i < sy1) ? y1i : sy1) : sy0) - by;
                v00 = tile[ry0 * REG_W + rx0];
                v10 = tile[ry0 * REG_W + rx1];
                v01 = tile[ry1 * REG_W + rx0];
                v11 = tile[ry1 * REG_W + rx1];
            } else {
                const int cx0 = (x0i > 0) ? ((x0i < IMG_W - 1) ? x0i : IMG_W - 1) : 0;
                const int cx1 = (x1i > 0) ? ((x1i < IMG_W - 1) ? x1i : IMG_W - 1) : 0;
                const int cy0 = (y0i > 0) ? ((y0i < IMG_H - 1) ? y0i : IMG_H - 1) : 0;
                const int cy1 = (y1i > 0) ? ((y1i < IMG_H - 1) ? y1i : IMG_H - 1) : 0;
                v00 = img[cy0 * IMG_W + cx0];
                v10 = img[cy0 * IMG_W + cx1];
                v01 = img[cy1 * IMG_W + cx0];
                v11 = img[cy1 * IMG_W + cx1];
            }

            const float e0 = (float)(v00 & 255u) * w00 + (float)(v10 & 255u) * w10 +
                             (float)(v01 & 255u) * w01 + (float)(v11 & 255u) * w11;
            const float e1 = (float)((v00 >> 8) & 255u) * w00 + (float)((v10 >> 8) & 255u) * w10 +
                             (float)((v01 >> 8) & 255u) * w01 + (float)((v11 >> 8) & 255u) * w11;
            const float e2 = (float)((v00 >> 16) & 255u) * w00 + (float)((v10 >> 16) & 255u) * w10 +
                             (float)((v01 >> 16) & 255u) * w01 + (float)((v11 >> 16) & 255u) * w11;

            const float d0 = r0 - truncf(e0);
            const float d1 = r1 - truncf(e1);
            const float d2 = r2 - truncf(e2);
            acc[n] += d0 * d0 + d1 * d1 + d2 * d2;
        }
    }

    // wave64 reduce, cross-wave LDS reduce, one atomic per block per flow
#pragma unroll
    for (int n = 0; n < NFLOW; ++n) {
#pragma unroll
        for (int off = 32; off > 0; off >>= 1)
            acc[n] += __shfl_down(acc[n], off, 64);
    }
    const int lane = threadIdx.x & 63;
    const int wid = threadIdx.x >> 6;
    if (lane == 0) {
#pragma unroll
        for (int n = 0; n < NFLOW; ++n) sacc[n][wid] = acc[n];
    }
    __syncthreads();
    if (threadIdx.x == 0) {
#pragma unroll
        for (int n = 0; n < NFLOW; ++n)
            atomicAdd(&sums[n], sacc[n][0] + sacc[n][1] + sacc[n][2] + sacc[n][3]);
    }
}

// ---------- finalize ----------
__global__ void psnr_finalize_kernel(const float* __restrict__ sums,
                                     float* __restrict__ out)
{
    if (threadIdx.x == 0 && blockIdx.x == 0) {
        double aggr = 0.0;
        for (int n = 0; n < NFLOW; ++n) {
            const double mse = (double)sums[n] / (3.0 * (double)HW);
            const double psnr = 10.0 * log10(255.0 * 255.0 / mse);
            double wgt = 1.0;
            for (int k = 0; k < NFLOW - n; ++k) wgt *= 0.85;
            aggr += psnr * wgt;
        }
        out[0] = (float)(-aggr);
    }
}

extern "C" void kernel_launch(void* const* d_in, const int* in_sizes, int n_in,
                              void* d_out, int out_size, void* d_ws, size_t ws_size,
                              hipStream_t stream) {
    const float* flow = (const float*)d_in[0];  // [5,1080,1920,2]
    const float* f1   = (const float*)d_in[1];  // [3,1080,1920]
    const float* f2   = (const float*)d_in[2];  // [3,1080,1920]
    float* out = (float*)d_out;

    float* sums = (float*)d_ws;                              // 5 floats @ 0
    unsigned int* img = (unsigned int*)((char*)d_ws + 256);  // HW u32 @ 256

    hipMemsetAsync(sums, 0, NFLOW * sizeof(float), stream);

    const int pack_blocks = (HW + 255) / 256;
    pack_u8_kernel<<<pack_blocks, 256, 0, stream>>>(f1, img);

    dim3 grid(IMG_W / TILE_W, (IMG_H + TILE_H - 1) / TILE_H);  // 30 x 34
    psnr_tile_kernel<<<grid, THREADS, 0, stream>>>((const float2*)flow, img, f2, sums);

    psnr_finalize_kernel<<<1, 64, 0, stream>>>(sums, out);
}

// Round 4
// 253.051 us; speedup vs baseline: 2.5843x; 1.1029x over previous
//
#include <hip/hip_runtime.h>
#include <math.h>

#define IMG_H 1080
#define IMG_W 1920
#define NFLOW 5
#define HW (IMG_H * IMG_W)

#define TILE_W 64
#define TILE_H 32
#define HALO 24
#define REG_W (TILE_W + 2 * HALO)   // 112
#define REG_H (TILE_H + 2 * HALO)   // 80
#define THREADS 256
#define GRID_X (IMG_W / TILE_W)                 // 30
#define GRID_Y ((IMG_H + TILE_H - 1) / TILE_H)  // 34
#define NBLOCKS (GRID_X * GRID_Y)               // 1020

// One fused kernel: stage+pack f1 tile (u8 RGB in u32), warped-SSE for all 5
// flows, block reduction + global atomics, last-block finalize -> out scalar.
__global__ __launch_bounds__(THREADS, 4) void psnr_mega_kernel(
    const float2* __restrict__ flow,   // [N][H][W] float2
    const float* __restrict__ f1,      // [3][H][W]
    const float* __restrict__ f2,      // [3][H][W]
    float* __restrict__ sums,          // [5] zeroed
    unsigned int* __restrict__ counter,// [1] zeroed
    float* __restrict__ out)           // [1]
{
    __shared__ unsigned int tile[REG_H * REG_W];  // 35840 B
    __shared__ float sacc[NFLOW][4];

    // --- bijective XCD-chunked swizzle (1020 = 8*127 + 4) ---
    const int wg = blockIdx.x;
    const int xcd = wg & 7;
    const int idx = wg >> 3;
    const int q = NBLOCKS >> 3;        // 127
    const int rr = NBLOCKS & 7;        // 4
    const int wgid = (xcd < rr ? xcd * (q + 1) : rr * (q + 1) + (xcd - rr) * q) + idx;
    const int tyb = wgid / GRID_X;
    const int txb = wgid - tyb * GRID_X;

    const int tx0 = txb * TILE_W;
    const int ty0 = tyb * TILE_H;
    const int bx = tx0 - HALO;
    const int by = ty0 - HALO;
    const int tid = threadIdx.x;

    // --- stage frame1 halo region, packing f32x3 -> u8x3 on the fly.
    // Out-of-image texels staged as 0 (matches zeros padding: weight 0 * 0).
    for (int r = tid; r < REG_H * REG_W; r += THREADS) {
        const int ry = r / REG_W;
        const int rx = r - ry * REG_W;
        const int gx = bx + rx;
        const int gy = by + ry;
        unsigned v = 0u;
        if ((unsigned)gx < (unsigned)IMG_W && (unsigned)gy < (unsigned)IMG_H) {
            const int gp = gy * IMG_W + gx;
            const unsigned c0 = (unsigned)(int)(f1[gp] + 0.5f);
            const unsigned c1 = (unsigned)(int)(f1[HW + gp] + 0.5f);
            const unsigned c2 = (unsigned)(int)(f1[2 * HW + gp] + 0.5f);
            v = c0 | (c1 << 8) | (c2 << 16);
        }
        tile[r] = v;
    }
    __syncthreads();

    float acc[NFLOW];
#pragma unroll
    for (int n = 0; n < NFLOW; ++n) acc[n] = 0.0f;

#pragma unroll 4
    for (int it = 0; it < (TILE_W * TILE_H) / THREADS; ++it) {
        const int qq = it * THREADS + tid;
        const int ly = qq >> 6;          // 64-wide rows: wave-uniform gy
        const int lx = qq & 63;
        const int gx = tx0 + lx;
        const int gy = ty0 + ly;
        if (gy >= IMG_H) continue;       // wave-uniform (bottom tiles)
        const int p = gy * IMG_W + gx;

        const float r0 = f2[p];
        const float r1 = f2[HW + p];
        const float r2 = f2[2 * HW + p];

#pragma unroll
        for (int n = 0; n < NFLOW; ++n) {
            const float2 fl = flow[n * HW + p];
            // all 4 taps provably inside staged rect iff flow within [-HALO, HALO)
            const bool ok = (fl.x >= -(float)HALO) && (fl.x < (float)HALO) &&
                            (fl.y >= -(float)HALO) && (fl.y < (float)HALO);

            const float px = (float)gx + fl.x;
            const float py = (float)gy + fl.y;
            const float x0f = floorf(px);
            const float y0f = floorf(py);
            const float wx1 = px - x0f;
            const float wy1 = py - y0f;
            const float wx0 = 1.0f - wx1;
            const float wy0 = 1.0f - wy1;

            const bool vx0 = (x0f >= 0.0f) && (x0f <= (float)(IMG_W - 1));
            const bool vx1 = (x0f >= -1.0f) && (x0f <= (float)(IMG_W - 2));
            const bool vy0 = (y0f >= 0.0f) && (y0f <= (float)(IMG_H - 1));
            const bool vy1 = (y0f >= -1.0f) && (y0f <= (float)(IMG_H - 2));

            const float w00 = (vx0 && vy0) ? (wx0 * wy0) : 0.0f;
            const float w10 = (vx1 && vy0) ? (wx1 * wy0) : 0.0f;
            const float w01 = (vx0 && vy1) ? (wx0 * wy1) : 0.0f;
            const float w11 = (vx1 && vy1) ? (wx1 * wy1) : 0.0f;

            float e0, e1, e2;
            if (ok) {
                const int x0i = (int)x0f;
                const int y0i = (int)y0f;
                const int ri = (y0i - by) * REG_W + (x0i - bx);
                const unsigned v00 = tile[ri];
                const unsigned v10 = tile[ri + 1];
                const unsigned v01 = tile[ri + REG_W];
                const unsigned v11 = tile[ri + REG_W + 1];

                e0 = (float)(v00 & 255u) * w00 + (float)(v10 & 255u) * w10 +
                     (float)(v01 & 255u) * w01 + (float)(v11 & 255u) * w11;
                e1 = (float)((v00 >> 8) & 255u) * w00 + (float)((v10 >> 8) & 255u) * w10 +
                     (float)((v01 >> 8) & 255u) * w01 + (float)((v11 >> 8) & 255u) * w11;
                e2 = (float)((v00 >> 16) & 255u) * w00 + (float)((v10 >> 16) & 255u) * w10 +
                     (float)((v01 >> 16) & 255u) * w01 + (float)((v11 >> 16) & 255u) * w11;
            } else {
                // rare outlier (P ~ 3e-6): exact f32 gather with clamping
                const int x0i = (int)fminf(fmaxf(x0f, 0.0f), (float)(IMG_W - 1));
                const int x1i = (int)fminf(fmaxf(x0f + 1.0f, 0.0f), (float)(IMG_W - 1));
                const int y0i = (int)fminf(fmaxf(y0f, 0.0f), (float)(IMG_H - 1));
                const int y1i = (int)fminf(fmaxf(y0f + 1.0f, 0.0f), (float)(IMG_H - 1));
                const int i00 = y0i * IMG_W + x0i;
                const int i10 = y0i * IMG_W + x1i;
                const int i01 = y1i * IMG_W + x0i;
                const int i11 = y1i * IMG_W + x1i;
                e0 = f1[i00] * w00 + f1[i10] * w10 + f1[i01] * w01 + f1[i11] * w11;
                e1 = f1[HW + i00] * w00 + f1[HW + i10] * w10 +
                     f1[HW + i01] * w01 + f1[HW + i11] * w11;
                e2 = f1[2 * HW + i00] * w00 + f1[2 * HW + i10] * w10 +
                     f1[2 * HW + i01] * w01 + f1[2 * HW + i11] * w11;
            }

            const float d0 = r0 - truncf(e0);
            const float d1 = r1 - truncf(e1);
            const float d2 = r2 - truncf(e2);
            acc[n] += d0 * d0 + d1 * d1 + d2 * d2;
        }
    }

    // --- wave64 reduce, cross-wave LDS reduce, one atomic per block per flow
#pragma unroll
    for (int n = 0; n < NFLOW; ++n) {
#pragma unroll
        for (int off = 32; off > 0; off >>= 1)
            acc[n] += __shfl_down(acc[n], off, 64);
    }
    const int lane = threadIdx.x & 63;
    const int wid = threadIdx.x >> 6;
    if (lane == 0) {
#pragma unroll
        for (int n = 0; n < NFLOW; ++n) sacc[n][wid] = acc[n];
    }
    __syncthreads();

    if (tid == 0) {
#pragma unroll
        for (int n = 0; n < NFLOW; ++n)
            atomicAdd(&sums[n], sacc[n][0] + sacc[n][1] + sacc[n][2] + sacc[n][3]);

        // --- last-block finalize (device-scope counter handshake)
        __threadfence();
        if (atomicAdd(counter, 1u) == (unsigned)(NBLOCKS - 1)) {
            __threadfence();
            double aggr = 0.0;
            for (int n = 0; n < NFLOW; ++n) {
                const float sn = __hip_atomic_load(&sums[n], __ATOMIC_RELAXED,
                                                   __HIP_MEMORY_SCOPE_AGENT);
                const double mse = (double)sn / (3.0 * (double)HW);
                const double psnr = 10.0 * log10(255.0 * 255.0 / mse);
                double wgt = 1.0;
                for (int k = 0; k < NFLOW - n; ++k) wgt *= 0.85;
                aggr += psnr * wgt;
            }
            out[0] = (float)(-aggr);
        }
    }
}

extern "C" void kernel_launch(void* const* d_in, const int* in_sizes, int n_in,
                              void* d_out, int out_size, void* d_ws, size_t ws_size,
                              hipStream_t stream) {
    const float* flow = (const float*)d_in[0];  // [5,1080,1920,2]
    const float* f1   = (const float*)d_in[1];  // [3,1080,1920]
    const float* f2   = (const float*)d_in[2];  // [3,1080,1920]
    float* out = (float*)d_out;

    float* sums = (float*)d_ws;                               // 5 floats @ 0
    unsigned int* counter = (unsigned int*)((char*)d_ws + 32);// u32 @ 32

    hipMemsetAsync(d_ws, 0, 64, stream);
    psnr_mega_kernel<<<NBLOCKS, THREADS, 0, stream>>>(
        (const float2*)flow, f1, f2, sums, counter, out);
}

// Round 5
// 227.812 us; speedup vs baseline: 2.8707x; 1.1108x over previous
//
#include <hip/hip_runtime.h>
#include <math.h>

#define IMG_H 1080
#define IMG_W 1920
#define NFLOW 5
#define HW (IMG_H * IMG_W)

#define TILE_W 64
#define TILE_H 32
#define HALO 24
#define REG_W (TILE_W + 2 * HALO)   // 112
#define REG_H (TILE_H + 2 * HALO)   // 80
#define THREADS 512
#define ITERS ((TILE_W * TILE_H) / THREADS)     // 4
#define GRID_X (IMG_W / TILE_W)                 // 30
#define GRID_Y ((IMG_H + TILE_H - 1) / TILE_H)  // 34
#define NBLOCKS (GRID_X * GRID_Y)               // 1020

// One fused kernel: stage+pack f1 tile (u8 RGB in u32), warped-SSE for all 5
// flows, block reduction + global atomics, last-block finalize -> out scalar.
// 512 threads/block, 4 blocks/CU -> 32 waves/CU for L3-latency hiding.
__global__ __launch_bounds__(THREADS, 8) void psnr_mega_kernel(
    const float2* __restrict__ flow,   // [N][H][W] float2
    const float* __restrict__ f1,      // [3][H][W]
    const float* __restrict__ f2,      // [3][H][W]
    float* __restrict__ sums,          // [5] zeroed
    unsigned int* __restrict__ counter,// [1] zeroed
    float* __restrict__ out)           // [1]
{
    __shared__ unsigned int tile[REG_H * REG_W];  // 35840 B
    __shared__ float sacc[NFLOW][THREADS / 64];

    // --- bijective XCD-chunked swizzle (1020 = 8*127 + 4) ---
    const int wg = blockIdx.x;
    const int xcd = wg & 7;
    const int idx = wg >> 3;
    const int q = NBLOCKS >> 3;        // 127
    const int rr = NBLOCKS & 7;        // 4
    const int wgid = (xcd < rr ? xcd * (q + 1) : rr * (q + 1) + (xcd - rr) * q) + idx;
    const int tyb = wgid / GRID_X;
    const int txb = wgid - tyb * GRID_X;

    const int tx0 = txb * TILE_W;
    const int ty0 = tyb * TILE_H;
    const int bx = tx0 - HALO;
    const int by = ty0 - HALO;
    const int tid = threadIdx.x;

    // --- stage frame1 halo region, packing f32x3 -> u8x3 on the fly.
    // Out-of-image texels staged as 0 (matches zeros padding: weight 0 * 0).
    for (int r = tid; r < REG_H * REG_W; r += THREADS) {
        const int ry = r / REG_W;
        const int rx = r - ry * REG_W;
        const int gx = bx + rx;
        const int gy = by + ry;
        unsigned v = 0u;
        if ((unsigned)gx < (unsigned)IMG_W && (unsigned)gy < (unsigned)IMG_H) {
            const int gp = gy * IMG_W + gx;
            const unsigned c0 = (unsigned)(int)(f1[gp] + 0.5f);
            const unsigned c1 = (unsigned)(int)(f1[HW + gp] + 0.5f);
            const unsigned c2 = (unsigned)(int)(f1[2 * HW + gp] + 0.5f);
            v = c0 | (c1 << 8) | (c2 << 16);
        }
        tile[r] = v;
    }
    __syncthreads();

    float acc[NFLOW];
#pragma unroll
    for (int n = 0; n < NFLOW; ++n) acc[n] = 0.0f;

    // per-flow processing (n static via unroll; fl already loaded)
    auto proc = [&](int n, float2 fl, int gx, int gy, float r0, float r1, float r2) {
        // all 4 taps provably inside staged rect iff flow within [-HALO, HALO)
        const bool ok = (fl.x >= -(float)HALO) && (fl.x < (float)HALO) &&
                        (fl.y >= -(float)HALO) && (fl.y < (float)HALO);

        const float px = (float)gx + fl.x;
        const float py = (float)gy + fl.y;
        const float x0f = floorf(px);
        const float y0f = floorf(py);
        const float wx1 = px - x0f;
        const float wy1 = py - y0f;
        const float wx0 = 1.0f - wx1;
        const float wy0 = 1.0f - wy1;

        const bool vx0 = (x0f >= 0.0f) && (x0f <= (float)(IMG_W - 1));
        const bool vx1 = (x0f >= -1.0f) && (x0f <= (float)(IMG_W - 2));
        const bool vy0 = (y0f >= 0.0f) && (y0f <= (float)(IMG_H - 1));
        const bool vy1 = (y0f >= -1.0f) && (y0f <= (float)(IMG_H - 2));

        const float w00 = (vx0 && vy0) ? (wx0 * wy0) : 0.0f;
        const float w10 = (vx1 && vy0) ? (wx1 * wy0) : 0.0f;
        const float w01 = (vx0 && vy1) ? (wx0 * wy1) : 0.0f;
        const float w11 = (vx1 && vy1) ? (wx1 * wy1) : 0.0f;

        float e0, e1, e2;
        if (ok) {
            const int x0i = (int)x0f;
            const int y0i = (int)y0f;
            const int ri = (y0i - by) * REG_W + (x0i - bx);
            const unsigned v00 = tile[ri];
            const unsigned v10 = tile[ri + 1];
            const unsigned v01 = tile[ri + REG_W];
            const unsigned v11 = tile[ri + REG_W + 1];

            e0 = (float)(v00 & 255u) * w00 + (float)(v10 & 255u) * w10 +
                 (float)(v01 & 255u) * w01 + (float)(v11 & 255u) * w11;
            e1 = (float)((v00 >> 8) & 255u) * w00 + (float)((v10 >> 8) & 255u) * w10 +
                 (float)((v01 >> 8) & 255u) * w01 + (float)((v11 >> 8) & 255u) * w11;
            e2 = (float)((v00 >> 16) & 255u) * w00 + (float)((v10 >> 16) & 255u) * w10 +
                 (float)((v01 >> 16) & 255u) * w01 + (float)((v11 >> 16) & 255u) * w11;
        } else {
            // rare outlier (P ~ 3e-6): exact f32 gather with clamping
            const int x0i = (int)fminf(fmaxf(x0f, 0.0f), (float)(IMG_W - 1));
            const int x1i = (int)fminf(fmaxf(x0f + 1.0f, 0.0f), (float)(IMG_W - 1));
            const int y0i = (int)fminf(fmaxf(y0f, 0.0f), (float)(IMG_H - 1));
            const int y1i = (int)fminf(fmaxf(y0f + 1.0f, 0.0f), (float)(IMG_H - 1));
            const int i00 = y0i * IMG_W + x0i;
            const int i10 = y0i * IMG_W + x1i;
            const int i01 = y1i * IMG_W + x0i;
            const int i11 = y1i * IMG_W + x1i;
            e0 = f1[i00] * w00 + f1[i10] * w10 + f1[i01] * w01 + f1[i11] * w11;
            e1 = f1[HW + i00] * w00 + f1[HW + i10] * w10 +
                 f1[HW + i01] * w01 + f1[HW + i11] * w11;
            e2 = f1[2 * HW + i00] * w00 + f1[2 * HW + i10] * w10 +
                 f1[2 * HW + i01] * w01 + f1[2 * HW + i11] * w11;
        }

        const float d0 = r0 - truncf(e0);
        const float d1 = r1 - truncf(e1);
        const float d2 = r2 - truncf(e2);
        acc[n] += d0 * d0 + d1 * d1 + d2 * d2;
    };

#pragma unroll
    for (int it = 0; it < ITERS; ++it) {
        const int qq = it * THREADS + tid;
        const int ly = qq >> 6;          // 64-wide rows: wave-uniform gy
        const int lx = qq & 63;
        const int gx = tx0 + lx;
        const int gy = ty0 + ly;
        if (gy >= IMG_H) continue;       // wave-uniform (bottom tiles)
        const int p = gy * IMG_W + gx;

        // batch ALL global loads for this iteration -> 8 independent L3 reqs
        const float2 fl0 = flow[p];
        const float2 fl1 = flow[HW + p];
        const float2 fl2 = flow[2 * HW + p];
        const float2 fl3 = flow[3 * HW + p];
        const float2 fl4 = flow[4 * HW + p];
        const float r0 = f2[p];
        const float r1 = f2[HW + p];
        const float r2 = f2[2 * HW + p];

        proc(0, fl0, gx, gy, r0, r1, r2);
        proc(1, fl1, gx, gy, r0, r1, r2);
        proc(2, fl2, gx, gy, r0, r1, r2);
        proc(3, fl3, gx, gy, r0, r1, r2);
        proc(4, fl4, gx, gy, r0, r1, r2);
    }

    // --- wave64 reduce, cross-wave LDS reduce, one atomic per block per flow
#pragma unroll
    for (int n = 0; n < NFLOW; ++n) {
#pragma unroll
        for (int off = 32; off > 0; off >>= 1)
            acc[n] += __shfl_down(acc[n], off, 64);
    }
    const int lane = threadIdx.x & 63;
    const int wid = threadIdx.x >> 6;
    if (lane == 0) {
#pragma unroll
        for (int n = 0; n < NFLOW; ++n) sacc[n][wid] = acc[n];
    }
    __syncthreads();

    if (tid == 0) {
        float bsum[NFLOW];
#pragma unroll
        for (int n = 0; n < NFLOW; ++n) {
            float s = 0.0f;
#pragma unroll
            for (int w = 0; w < THREADS / 64; ++w) s += sacc[n][w];
            bsum[n] = s;
        }
#pragma unroll
        for (int n = 0; n < NFLOW; ++n)
            atomicAdd(&sums[n], bsum[n]);

        // --- last-block finalize (device-scope counter handshake)
        __threadfence();
        if (atomicAdd(counter, 1u) == (unsigned)(NBLOCKS - 1)) {
            __threadfence();
            double aggr = 0.0;
            for (int n = 0; n < NFLOW; ++n) {
                const float sn = __hip_atomic_load(&sums[n], __ATOMIC_RELAXED,
                                                   __HIP_MEMORY_SCOPE_AGENT);
                const double mse = (double)sn / (3.0 * (double)HW);
                const double psnr = 10.0 * log10(255.0 * 255.0 / mse);
                double wgt = 1.0;
                for (int k = 0; k < NFLOW - n; ++k) wgt *= 0.85;
                aggr += psnr * wgt;
            }
            out[0] = (float)(-aggr);
        }
    }
}

extern "C" void kernel_launch(void* const* d_in, const int* in_sizes, int n_in,
                              void* d_out, int out_size, void* d_ws, size_t ws_size,
                              hipStream_t stream) {
    const float* flow = (const float*)d_in[0];  // [5,1080,1920,2]
    const float* f1   = (const float*)d_in[1];  // [3,1080,1920]
    const float* f2   = (const float*)d_in[2];  // [3,1080,1920]
    float* out = (float*)d_out;

    float* sums = (float*)d_ws;                               // 5 floats @ 0
    unsigned int* counter = (unsigned int*)((char*)d_ws + 32);// u32 @ 32

    hipMemsetAsync(d_ws, 0, 64, stream);
    psnr_mega_kernel<<<NBLOCKS, THREADS, 0, stream>>>(
        (const float2*)flow, f1, f2, sums, counter, out);
}